// Round 13
// baseline (3499.753 us; speedup 1.0000x reference)
//
#include <hip/hip_runtime.h>

#define NNODE 1000
#define NBATCH 8
#define SEQL 12
#define NHEAD 8
#define DHEAD 16
#define HID 128
#define NEDGE 16000
#define NROWS (NBATCH*NNODE)   // 8000
#define RPB 32                 // rows per persistent block
#define NBLK_P 256             // 8 batch-groups x 32 slots; 1 block/CU
#define NBLK_B 32              // blocks per batch = barrier width
#define BARSTRIDE 64           // ints between per-batch counters (256 B)
#define PTHREADS 1024
#define ORPB 16
#define NBLK_O (NROWS/ORPB)    // 500
#define DT 0.25f
#define ECAP 768               // LDS edge cache (block mean 512)
#define SPIN_LIMIT 100000ULL   // 1 ms escape hatch (finite wrong-run, not hang)
#define WSTRIDE 136            // padded K-stride (u16); 272 B row = 16B-aligned
#define WLO (128*WSTRIDE)      // u16 offset of the lo-residual matrix

typedef unsigned short u16;
typedef unsigned int   u32;
typedef unsigned long long u64;
typedef __attribute__((ext_vector_type(8))) short bf16x8;
typedef __attribute__((ext_vector_type(4))) float f32x4;

__device__ __forceinline__ u16 f2bf(float f){
  u32 x = __float_as_uint(f);
  return (u16)((x + 0x7fffu + ((x>>16)&1u)) >> 16);
}
__device__ __forceinline__ float bf2f(u16 u){ return __uint_as_float(((u32)u)<<16); }

// ---- agent-scope (MALL point-of-coherence) h exchange ----
__device__ __forceinline__ u64 ld_agent_u64(const u16* p){
  return __hip_atomic_load(reinterpret_cast<const u64*>(p),
                           __ATOMIC_RELAXED, __HIP_MEMORY_SCOPE_AGENT);
}
__device__ __forceinline__ void st_agent_u64(u16* p, u64 v){
  __hip_atomic_store(reinterpret_cast<u64*>(p), v,
                     __ATOMIC_RELAXED, __HIP_MEMORY_SCOPE_AGENT);
}

// ---- per-batch barrier: release fetch_add orders prior sc1 stores; no fences ----
__device__ __forceinline__ void grid_bar(int* bar, int target){
  __syncthreads();
  if (threadIdx.x == 0){
    __hip_atomic_fetch_add(bar, 1, __ATOMIC_RELEASE, __HIP_MEMORY_SCOPE_AGENT);
    unsigned long long t0 = __builtin_amdgcn_s_memrealtime();
    while (__hip_atomic_load(bar, __ATOMIC_RELAXED, __HIP_MEMORY_SCOPE_AGENT) < target){
      __builtin_amdgcn_s_sleep(2);
      if (__builtin_amdgcn_s_memrealtime() - t0 > SPIN_LIMIT) break;
    }
  }
  __syncthreads();
}

// copy a 128x128 fp32 matrix global->LDS, NT threads (GRU + out_kernel path)
template<int NT>
__device__ __forceinline__ void load_W(float* Wl, const float* g, int tid){
  #pragma unroll
  for (int c = 0; c < (HID*HID/4)/NT; ++c){
    int e = (c*NT + tid)*4;
    *reinterpret_cast<float4*>(Wl + e) = *reinterpret_cast<const float4*>(g + e);
  }
}

// split-precision transposed load: W[k][n] fp32 -> WbT[n][k] hi/lo bf16
__device__ __forceinline__ void load_WT_split(u16* WbT, const float* g, int tid){
  #pragma unroll
  for (int c = 0; c < 16; ++c){
    int flat = c*PTHREADS + tid;        // = k*128 + n
    int k = flat >> 7, n = flat & 127;
    float v = g[flat];
    u16 hi = f2bf(v);
    u16 lo = f2bf(v - bf2f(hi));
    WbT[n*WSTRIDE + k]       = hi;
    WbT[WLO + n*WSTRIDE + k] = lo;
  }
}

// one row, 4 cols: o[j] = sum_k yt[rs][k]*Wl[k][fg*4+j]  (fp32, GRU path)
__device__ __forceinline__ void gemm128_1(const float* Wl, const float* yt, int fg, int rs,
                                          float o[4]){
  float a0[4]={0.f,0.f,0.f,0.f};
  #pragma unroll 4
  for (int k=0;k<HID;k+=4){
    float4 ya = *reinterpret_cast<const float4*>(yt + rs*HID + k);
    #pragma unroll
    for (int kk=0;kk<4;++kk){
      const float* wr = Wl + (k+kk)*HID + fg*4;
      float av = (&ya.x)[kk];
      #pragma unroll
      for (int i=0;i<4;++i) a0[i] = fmaf(wr[i], av, a0[i]);
    }
  }
  #pragma unroll
  for (int i=0;i<4;++i) o[i]=a0[i];
}

// two rows (rs, rs+RSTEP), 4 cols — used by out_kernel
template<int RSTEP>
__device__ __forceinline__ void gemm128(const float* Wl, const float* yt, int fg, int rs,
                                        float o0[4], float o1[4]){
  float a0[4]={0.f,0.f,0.f,0.f}, a1[4]={0.f,0.f,0.f,0.f};
  #pragma unroll 4
  for (int k=0;k<HID;k+=4){
    float4 ya = *reinterpret_cast<const float4*>(yt + rs*HID + k);
    float4 yb = *reinterpret_cast<const float4*>(yt + (rs+RSTEP)*HID + k);
    #pragma unroll
    for (int kk=0;kk<4;++kk){
      const float* wr = Wl + (k+kk)*HID + fg*4;
      float av = (&ya.x)[kk];
      float bv = (&yb.x)[kk];
      #pragma unroll
      for (int i=0;i<4;++i){
        float w = wr[i];
        a0[i] = fmaf(w, av, a0[i]);
        a1[i] = fmaf(w, bv, a1[i]);
      }
    }
  }
  #pragma unroll
  for (int i=0;i<4;++i){ o0[i]=a0[i]; o1[i]=a1[i]; }
}

// pack 16 fp32 -> 16 bf16 into yt_bf[rA][off16..off16+15]  (32 B, 16B-aligned)
__device__ __forceinline__ void pack_y16(u16* yt_bf, int rA, int off16, const float y[16]){
  uint4 w0, w1;
  w0.x = (u32)f2bf(y[0])  | ((u32)f2bf(y[1])<<16);
  w0.y = (u32)f2bf(y[2])  | ((u32)f2bf(y[3])<<16);
  w0.z = (u32)f2bf(y[4])  | ((u32)f2bf(y[5])<<16);
  w0.w = (u32)f2bf(y[6])  | ((u32)f2bf(y[7])<<16);
  w1.x = (u32)f2bf(y[8])  | ((u32)f2bf(y[9])<<16);
  w1.y = (u32)f2bf(y[10]) | ((u32)f2bf(y[11])<<16);
  w1.z = (u32)f2bf(y[12]) | ((u32)f2bf(y[13])<<16);
  w1.w = (u32)f2bf(y[14]) | ((u32)f2bf(y[15])<<16);
  *reinterpret_cast<uint4*>(yt_bf + rA*WSTRIDE + off16)     = w0;
  *reinterpret_cast<uint4*>(yt_bf + rA*WSTRIDE + off16 + 8) = w1;
}

// one edge, one full head (16 dims local): el computed without any shuffle
__device__ __forceinline__ void edge_acc16(u64 x0, u64 x1, u64 x2, u64 x3,
                                           const float alA[16], float erh,
                                           float& sum, float acc[16]){
  float hv[16];
  const u64 xs[4] = {x0, x1, x2, x3};
  #pragma unroll
  for (int q=0;q<4;++q){
    hv[q*4+0]=bf2f((u16)xs[q]);        hv[q*4+1]=bf2f((u16)(xs[q]>>16));
    hv[q*4+2]=bf2f((u16)(xs[q]>>32));  hv[q*4+3]=bf2f((u16)(xs[q]>>48));
  }
  float ep = 0.f;
  #pragma unroll
  for (int i=0;i<16;++i) ep = fmaf(alA[i], hv[i], ep);
  const float x = ep + erh;
  const float w = __expf(fminf(fmaxf(x, 0.2f*x), 30.f));
  sum += w;
  #pragma unroll
  for (int i=0;i<16;++i) acc[i] = fmaf(w, hv[i], acc[i]);
}

// MFMA h-stage: yt_bf holds y (bf16); WbT holds w_gat^T hi/lo.
__device__ __forceinline__ void h_stage(u16* yt_bf, const u16* WbT,
    int mt, int nt, int quad, int lc,
    int fg, int rs, int rowF, bool actF,
    u16* __restrict__ h_wr, float* er_l, const float ar4[4])
{
  f32x4 c = {0.f, 0.f, 0.f, 0.f};
  const u16* arow = yt_bf + (mt*16 + lc)*WSTRIDE;
  const u16* brow = WbT  + (nt*16 + lc)*WSTRIDE;
  #pragma unroll
  for (int k0 = 0; k0 < 4; ++k0){
    const int off = k0*32 + quad*8;
    bf16x8 a  = *reinterpret_cast<const bf16x8*>(arow + off);
    bf16x8 bh = *reinterpret_cast<const bf16x8*>(brow + off);
    bf16x8 bl = *reinterpret_cast<const bf16x8*>(brow + WLO + off);
    c = __builtin_amdgcn_mfma_f32_16x16x32_bf16(a, bh, c, 0, 0, 0);
    c = __builtin_amdgcn_mfma_f32_16x16x32_bf16(a, bl, c, 0, 0, 0);
  }
  __syncthreads();              // all A-reads of yt_bf complete
  {
    const int col = nt*16 + lc;
    #pragma unroll
    for (int r = 0; r < 4; ++r)
      yt_bf[(mt*16 + quad*4 + r)*WSTRIDE + col] = f2bf(c[r]);
  }
  __syncthreads();              // h bf16 visible block-wide
  const u64 pk = *reinterpret_cast<const u64*>(yt_bf + rs*WSTRIDE + fg*4);
  if (actF) st_agent_u64(h_wr + (size_t)rowF*HID + fg*4, pk);
  float er = 0.f;
  er = fmaf(bf2f((u16)pk),       ar4[0], er);
  er = fmaf(bf2f((u16)(pk>>16)), ar4[1], er);
  er = fmaf(bf2f((u16)(pk>>32)), ar4[2], er);
  er = fmaf(bf2f((u16)(pk>>48)), ar4[3], er);
  er += __shfl_xor(er,1); er += __shfl_xor(er,2);
  if ((fg & 3) == 0 && actF) er_l[rs*NHEAD + (fg>>2)] = er;
}

// Build CSR (edges sorted by dst); zero the 8 per-batch barrier counters.
__global__ void csr_kernel(const int* __restrict__ src, const int* __restrict__ dst,
                           int* __restrict__ row_start, int* __restrict__ edge_src,
                           int* __restrict__ bar){
  __shared__ int cnt[1024];
  __shared__ int scanb[1024];
  __shared__ int cur[1024];
  int tid = threadIdx.x;
  if (tid < NBATCH*BARSTRIDE) bar[tid] = 0;
  cnt[tid] = 0;
  __syncthreads();
  for (int e = tid; e < NEDGE; e += 1024) atomicAdd(&cnt[dst[e]], 1);
  __syncthreads();
  int v = cnt[tid];
  scanb[tid] = v;
  __syncthreads();
  for (int off=1; off<1024; off<<=1){
    int t = (tid >= off) ? scanb[tid-off] : 0;
    __syncthreads();
    scanb[tid] += t;
    __syncthreads();
  }
  int incl = scanb[tid];
  if (tid < NNODE){ cur[tid] = incl - v; row_start[tid+1] = incl; }
  if (tid == 0) row_start[0] = 0;
  __syncthreads();
  for (int e = tid; e < NEDGE; e += 1024){
    int d = dst[e];
    int pos = atomicAdd(&cur[d], 1);
    edge_src[pos] = src[e];
  }
}

struct PArgs {
  u16* hb0; u16* hb1; float* y_out;
  const int* row_start; const int* edge_src;
  const float* w_gat; const float* a_l; const float* a_r;
  const float* inputs; const float* w_in; const float* b_in;
  const float* w_W; const float* b_W; const float* w_U; const float* b_U;
  int* bar;
};

__global__ void __launch_bounds__(PTHREADS, 4) persist(PArgs p)
{
  __shared__ __align__(16) u16 WbT[2*128*WSTRIDE];  // 68 KB: w_gat^T hi/lo (bf16)
  __shared__ __align__(16) u16 yt_bf[RPB*WSTRIDE];  // 8.5 KB: y then h (bf16)
  __shared__ float zt[RPB*HID];                     // 16 KB: fp32 GRU/LN staging
  __shared__ int   esrc_l[ECAP];
  __shared__ int   eoff[RPB+1];
  __shared__ int   degs_s[RPB];
  __shared__ float er_l[RPB*NHEAD];                 // total ~98 KB -> 1 block/CU
  float* const Wlf = reinterpret_cast<float*>(WbT); // 64 KB fp32 overlay (GRU)

  const int tid  = threadIdx.x;
  const int bat   = blockIdx.x & 7;            // batch index (XCD heuristic)
  const int slot  = blockIdx.x >> 3;           // 0..31
  const int row0  = bat * NNODE + slot * RPB;
  const int nrows = (slot == 31) ? (NNODE - 31*RPB) : RPB;   // 8 or 32
  int* const bar_b = p.bar + bat * BARSTRIDE;
  // layout A (gather): 8 heads x 4 edge-segments per row, 32 rows.
  // One full head (16 dims) per thread: el is shuffle-free, exp once/edge,
  // and the per-thread edge chain is deg/4 (halves the max-degree tail).
  const int tA = tid & 7, seg = (tid >> 3) & 3, rA = tid >> 5;
  const bool actA = rA < nrows;
  const int nA     = slot*RPB + rA;
  const int nAs    = actA ? nA : 0;
  const int sbase  = bat * NNODE;
  const int off16  = tA * 16;                  // head tA's dims
  // layout F (epilogue/LN): 32 col-groups (4 cols) x 32 rows
  const int fg = tid & 31, rs = tid >> 5;
  const bool actF = rs < nrows;
  const int rowF = row0 + rs;
  const int hd2 = fg >> 2, db = (fg & 3) * 4;
  // MFMA ids: 16 waves = 2 M-tiles x 8 N-tiles
  const int wv = tid >> 6, lane = tid & 63, quad = lane >> 4, lc = lane & 15;
  const int mt = wv & 1, nt = wv >> 1;

  // ---- one-time: per-block edge cache ----
  int s0r = 0, degr = 0;
  if (actA){ s0r = p.row_start[nA]; degr = p.row_start[nA+1] - s0r; }
  if ((tid & 31) == 0) degs_s[rA] = degr;
  __syncthreads();
  if (tid == 0){
    int o = 0;
    #pragma unroll
    for (int r = 0; r < RPB; ++r){ eoff[r] = o; o += degs_s[r]; }
    eoff[RPB] = o;
  }
  __syncthreads();
  const int* eptr;
  if (eoff[RPB] <= ECAP){
    const int eb = eoff[rA];
    for (int e = (tid & 31); e < degr; e += 32) esrc_l[eb + e] = p.edge_src[s0r + e];
    eptr = esrc_l + eb;
  } else {
    eptr = p.edge_src + s0r;   // statistically never; correctness fallback
  }

  // ---- one-time: per-thread constants ----
  float alA[16];
  #pragma unroll
  for (int i=0;i<16;++i) alA[i] = p.a_l[tA*DHEAD + i];   // head tA, all 16 dims
  float ar4[4];
  #pragma unroll
  for (int i=0;i<4;++i) ar4[i] = p.a_r[hd2*DHEAD + db + i];

  load_WT_split(WbT, p.w_gat, tid);

  // ---- init: y0 = inputs[:,0]@w_in + b_in ----
  float yb16[16], ya16[16];
  {
    const float x0 = p.inputs[((bat*SEQL + 0)*NNODE + nAs)*2 + 0];
    const float x1 = p.inputs[((bat*SEQL + 0)*NNODE + nAs)*2 + 1];
    #pragma unroll
    for (int i=0;i<16;++i){
      int f = off16 + i;
      yb16[i] = x0*p.w_in[f] + x1*p.w_in[HID+f] + p.b_in[f];
    }
    if (seg == 0) pack_y16(yt_bf, rA, off16, yb16);
  }
  __syncthreads();     // yt_bf, WbT, esrc_l staged
  h_stage(yt_bf, WbT, mt, nt, quad, lc, fg, rs, rowF, actF, p.hb0, er_l, ar4);

  int step = 1;
  grid_bar(bar_b, NBLK_B * step); ++step;

  // per-segment edge range (contiguous quarters)
  const int e_lo = (degr * seg)     >> 2;
  const int e_hi = (degr * (seg+1)) >> 2;

  int rd = 0;
  for (int idx = 0; idx < SEQL; ++idx){
    for (int st = 0; st < 4; ++st){
      for (int j = 1; j <= 4; ++j){
        const u16* __restrict__ h_rd = rd ? p.hb1 : p.hb0;
        u16* __restrict__ h_wr       = rd ? p.hb0 : p.hb1;

        // ---- gather: per-head softmax aggregation (2-edge batches = 8
        // in-flight 8B loads, round-10's sweet spot) ----
        float acc[16];
        #pragma unroll
        for (int i=0;i<16;++i) acc[i] = 0.f;
        float sum = 0.f;
        {
          const float erh = er_l[rA*NHEAD + tA];
          int e = e_lo;
          for (; e + 2 <= e_hi; e += 2){
            const int sA = sbase + eptr[e];
            const int sB = sbase + eptr[e+1];
            const u16* pa = h_rd + (size_t)sA*HID + off16;
            const u16* pb = h_rd + (size_t)sB*HID + off16;
            u64 a0 = ld_agent_u64(pa);
            u64 a1 = ld_agent_u64(pa + 4);
            u64 a2 = ld_agent_u64(pa + 8);
            u64 a3 = ld_agent_u64(pa + 12);
            u64 b0 = ld_agent_u64(pb);
            u64 b1 = ld_agent_u64(pb + 4);
            u64 b2 = ld_agent_u64(pb + 8);
            u64 b3 = ld_agent_u64(pb + 12);
            edge_acc16(a0, a1, a2, a3, alA, erh, sum, acc);
            edge_acc16(b0, b1, b2, b3, alA, erh, sum, acc);
          }
          if (e < e_hi){
            const int sA = sbase + eptr[e];
            const u16* pa = h_rd + (size_t)sA*HID + off16;
            u64 a0 = ld_agent_u64(pa);
            u64 a1 = ld_agent_u64(pa + 4);
            u64 a2 = ld_agent_u64(pa + 8);
            u64 a3 = ld_agent_u64(pa + 12);
            edge_acc16(a0, a1, a2, a3, alA, erh, sum, acc);
          }
        }
        // combine the 4 segments (lanes ^8, ^16 = same row+head, other segs)
        sum += __shfl_xor(sum, 8);
        sum += __shfl_xor(sum, 16);
        #pragma unroll
        for (int i=0;i<16;++i){
          acc[i] += __shfl_xor(acc[i], 8);
          acc[i] += __shfl_xor(acc[i], 16);
        }
        const float inv = 1.f / (sum + 1e-16f);
        #pragma unroll
        for (int i=0;i<16;++i) acc[i] *= inv;

        // ---- RK4 register update (duplicated across segs, identical) ----
        const bool is5 = (st == 3) && (j == 4);
        float nxt[16];
        if (j == 1){
          #pragma unroll
          for (int i=0;i<16;++i){ ya16[i] = fmaf(DT/6.f, acc[i], yb16[i]);
                                  nxt[i]  = fmaf(0.5f*DT, acc[i], yb16[i]); }
        } else if (j == 2){
          #pragma unroll
          for (int i=0;i<16;++i){ ya16[i] = fmaf(DT/3.f, acc[i], ya16[i]);
                                  nxt[i]  = fmaf(0.5f*DT, acc[i], yb16[i]); }
        } else if (j == 3){
          #pragma unroll
          for (int i=0;i<16;++i){ ya16[i] = fmaf(DT/3.f, acc[i], ya16[i]);
                                  nxt[i]  = fmaf(DT, acc[i], yb16[i]); }
        } else {
          #pragma unroll
          for (int i=0;i<16;++i) nxt[i] = fmaf(DT/6.f, acc[i], ya16[i]);
          if (!is5){
            #pragma unroll
            for (int i=0;i<16;++i) yb16[i] = nxt[i];
          }
        }

        if (!is5){
          if (seg == 0) pack_y16(yt_bf, rA, off16, nxt);
          __syncthreads();
          h_stage(yt_bf, WbT, mt, nt, quad, lc, fg, rs, rowF, actF, h_wr, er_l, ar4);
          grid_bar(bar_b, NBLK_B * step); ++step;
          rd ^= 1;
          continue;
        }

        // ---- end of interval: GRU (fp32 vector) / LN / state handoff ----
        const bool last = (idx == SEQL-1);
        if (seg == 0){
          #pragma unroll
          for (int q=0;q<4;++q)
            *reinterpret_cast<float4*>(zt + rA*HID + off16 + q*4) =
                make_float4(nxt[q*4+0], nxt[q*4+1], nxt[q*4+2], nxt[q*4+3]);
        }
        float z4[4];
        if (idx > 0){
          load_W<PTHREADS>(Wlf, p.w_W, tid);     // overlays WbT (restored below)
          __syncthreads();                       // zt(y_new) + w_W ready
          gemm128_1(Wlf, zt, fg, rs, z4);        // z = y_new @ w_W
          __syncthreads();                       // gemm reads done
          {
            const float x0 = p.inputs[((bat*SEQL + idx)*NNODE + nAs)*2 + 0];
            const float x1 = p.inputs[((bat*SEQL + idx)*NNODE + nAs)*2 + 1];
            if (seg == 0){
              float hv[16];
              #pragma unroll
              for (int i=0;i<16;++i){
                int f = off16 + i;
                hv[i] = x0*p.w_in[f] + x1*p.w_in[HID+f] + p.b_in[f];
              }
              #pragma unroll
              for (int q=0;q<4;++q)
                *reinterpret_cast<float4*>(zt + rA*HID + off16 + q*4) =
                    make_float4(hv[q*4+0], hv[q*4+1], hv[q*4+2], hv[q*4+3]);
            }
          }
          load_W<PTHREADS>(Wlf, p.w_U, tid);
          __syncthreads();
          float u4[4];
          gemm128_1(Wlf, zt, fg, rs, u4);        // u = h_in @ w_U
          #pragma unroll
          for (int i=0;i<4;++i)
            z4[i] = tanhf(z4[i] + u4[i] + p.b_W[fg*4+i] + p.b_U[fg*4+i]);
        } else {
          __syncthreads();                       // zt(y_new) visible in F layout
          #pragma unroll
          for (int i=0;i<4;++i) z4[i] = zt[rs*HID + fg*4 + i];
        }
        // LayerNorm over 128 features (32 fg lanes)
        {
          float sv=0.f, qv=0.f;
          #pragma unroll
          for (int i=0;i<4;++i){ sv+=z4[i]; qv+=z4[i]*z4[i]; }
          #pragma unroll
          for (int off=1; off<32; off<<=1){
            sv += __shfl_xor(sv, off); qv += __shfl_xor(qv, off);
          }
          float mu = sv*(1.f/HID);
          float r  = rsqrtf(qv*(1.f/HID) - mu*mu + 1e-5f);
          #pragma unroll
          for (int i=0;i<4;++i) z4[i] = (z4[i]-mu)*r;
        }
        __syncthreads();                         // all zt readers done
        *reinterpret_cast<float4*>(zt + rs*HID + fg*4) = make_float4(z4[0],z4[1],z4[2],z4[3]);
        if (last){
          if (actF)
            *reinterpret_cast<float4*>(p.y_out + (size_t)rowF*HID + fg*4) =
                make_float4(z4[0],z4[1],z4[2],z4[3]);
          // final stage: no more barriers; blocks exit uniformly
        } else {
          __syncthreads();                       // zt(z) visible
          if (idx > 0) load_WT_split(WbT, p.w_gat, tid);  // restore w_gat^T hi/lo
          #pragma unroll
          for (int i=0;i<16;++i) yb16[i] = zt[rA*HID + off16 + i];  // new y state
          if (seg == 0) pack_y16(yt_bf, rA, off16, yb16);
          __syncthreads();
          h_stage(yt_bf, WbT, mt, nt, quad, lc, fg, rs, rowF, actF, h_wr, er_l, ar4);
          grid_bar(bar_b, NBLK_B * step); ++step;
          rd ^= 1;
        }
      }
    }
  }
}

// out = tanh(ret @ w_o1 + b_o1) @ w_o2 + b_o2, fp32 output
__global__ void __launch_bounds__(256, 2) out_kernel(
    const float* __restrict__ y_base,
    const float* __restrict__ w_o1, const float* __restrict__ b_o1,
    const float* __restrict__ w_o2, const float* __restrict__ b_o2,
    float* __restrict__ out)
{
  __shared__ float Wl[HID*HID];
  __shared__ float yt[ORPB*HID];
  const int tid = threadIdx.x;
  const int row0 = blockIdx.x * ORPB;
  const int rA = tid >> 4, tA = tid & 15;
  const int rowA = row0 + rA;
  {
    float4 v0 = *reinterpret_cast<const float4*>(y_base + rowA*HID + tA*8);
    float4 v1 = *reinterpret_cast<const float4*>(y_base + rowA*HID + tA*8 + 4);
    *reinterpret_cast<float4*>(yt + rA*HID + tA*8)     = v0;
    *reinterpret_cast<float4*>(yt + rA*HID + tA*8 + 4) = v1;
  }
  load_W<256>(Wl, w_o1, tid);
  __syncthreads();
  const int fg = tid & 31, rs = tid >> 5;
  float t0[4], t1[4];
  gemm128<8>(Wl, yt, fg, rs, t0, t1);
  #pragma unroll
  for (int i=0;i<4;++i){
    float bb = b_o1[fg*4+i];
    t0[i] = tanhf(t0[i] + bb);
    t1[i] = tanhf(t1[i] + bb);
  }
  __syncthreads();
  *reinterpret_cast<float4*>(yt + rs*HID + fg*4)     = make_float4(t0[0],t0[1],t0[2],t0[3]);
  *reinterpret_cast<float4*>(yt + (rs+8)*HID + fg*4) = make_float4(t1[0],t1[1],t1[2],t1[3]);
  load_W<256>(Wl, w_o2, tid);
  __syncthreads();
  float o0[4], o1[4];
  gemm128<8>(Wl, yt, fg, rs, o0, o1);
  const int rowF0 = row0 + rs, rowF1 = row0 + rs + 8;
  *reinterpret_cast<float4*>(out + rowF0*HID + fg*4) =
      make_float4(o0[0]+b_o2[fg*4+0], o0[1]+b_o2[fg*4+1], o0[2]+b_o2[fg*4+2], o0[3]+b_o2[fg*4+3]);
  *reinterpret_cast<float4*>(out + rowF1*HID + fg*4) =
      make_float4(o1[0]+b_o2[fg*4+0], o1[1]+b_o2[fg*4+1], o1[2]+b_o2[fg*4+2], o1[3]+b_o2[fg*4+3]);
}

extern "C" void kernel_launch(void* const* d_in, const int* in_sizes, int n_in,
                              void* d_out, int out_size, void* d_ws, size_t ws_size,
                              hipStream_t stream)
{
  const float* inputs = (const float*)d_in[0];
  const int* src      = (const int*)d_in[1];
  const int* dst      = (const int*)d_in[2];
  const float* w_in   = (const float*)d_in[3];
  const float* b_in   = (const float*)d_in[4];
  const float* w_gat  = (const float*)d_in[5];
  const float* a_l    = (const float*)d_in[6];
  const float* a_r    = (const float*)d_in[7];
  const float* w_W    = (const float*)d_in[8];
  const float* b_W    = (const float*)d_in[9];
  const float* w_U    = (const float*)d_in[10];
  const float* b_U    = (const float*)d_in[11];
  const float* w_o1   = (const float*)d_in[12];
  const float* b_o1   = (const float*)d_in[13];
  const float* w_o2   = (const float*)d_in[14];
  const float* b_o2   = (const float*)d_in[15];

  const size_t RH = (size_t)NROWS * HID;    // 1,024,000
  float* y_out = reinterpret_cast<float*>(d_ws);            // RH floats
  u16*   hbuf  = reinterpret_cast<u16*>(y_out + RH);        // 2*RH bf16
  u16*   hb0   = hbuf;
  u16*   hb1   = hbuf + RH;
  int*   I     = reinterpret_cast<int*>(hbuf + 2*RH);
  int* row_start = I;
  int* edge_src  = I + 1024;
  int* bar       = I + 1024 + NEDGE;

  size_t need = RH*sizeof(float) + 2*RH*sizeof(u16)
              + (size_t)(1024 + NEDGE + NBATCH*BARSTRIDE)*sizeof(int);
  if (ws_size < need) return;

  csr_kernel<<<1, 1024, 0, stream>>>(src, dst, row_start, edge_src, bar);

  PArgs pa;
  pa.hb0 = hb0; pa.hb1 = hb1; pa.y_out = y_out;
  pa.row_start = row_start; pa.edge_src = edge_src;
  pa.w_gat = w_gat; pa.a_l = a_l; pa.a_r = a_r;
  pa.inputs = inputs; pa.w_in = w_in; pa.b_in = b_in;
  pa.w_W = w_W; pa.b_W = b_W; pa.w_U = w_U; pa.b_U = b_U;
  pa.bar = bar;

  persist<<<NBLK_P, PTHREADS, 0, stream>>>(pa);

  out_kernel<<<NBLK_O, 256, 0, stream>>>(y_out, w_o1, b_o1, w_o2, b_o2, (float*)d_out);
}

// Round 14
// 2748.299 us; speedup vs baseline: 1.2734x; 1.2734x over previous
//
#include <hip/hip_runtime.h>

#define NNODE 1000
#define NBATCH 8
#define SEQL 12
#define NHEAD 8
#define DHEAD 16
#define HID 128
#define NEDGE 16000
#define NROWS (NBATCH*NNODE)   // 8000
#define RPB 32                 // rows per persistent block
#define NBLK_P 256             // 8 batch-groups x 32 slots; 1 block/CU
#define NBLK_B 32              // blocks per batch = barrier width
#define BARSTRIDE 64           // ints between per-batch counters (256 B)
#define PTHREADS 1024
#define ORPB 16
#define NBLK_O (NROWS/ORPB)    // 500
#define DT 0.25f
#define ECAP 768               // LDS edge cache (block mean 512)
#define SPIN_LIMIT 100000ULL   // 1 ms escape hatch (finite wrong-run, not hang)
#define WSTRIDE 136            // padded K-stride (u16)
#define WLO (128*WSTRIDE)      // u16 offset of the lo-residual matrix

typedef unsigned short u16;
typedef unsigned int   u32;
typedef unsigned long long u64;
typedef __attribute__((ext_vector_type(8))) short bf16x8;
typedef __attribute__((ext_vector_type(4))) float f32x4;

__device__ __forceinline__ u16 f2bf(float f){
  u32 x = __float_as_uint(f);
  return (u16)((x + 0x7fffu + ((x>>16)&1u)) >> 16);
}
__device__ __forceinline__ float bf2f(u16 u){ return __uint_as_float(((u32)u)<<16); }

// ---- agent-scope (MALL point-of-coherence) h exchange ----
// sc1 write-through streams to MALL during the stage; rounds 11-13 showed
// every perturbation (L2-local stores, 8-deep MLP, head-per-thread layout)
// regresses. This is the measured optimum of the exchange.
__device__ __forceinline__ u64 ld_agent_u64(const u16* p){
  return __hip_atomic_load(reinterpret_cast<const u64*>(p),
                           __ATOMIC_RELAXED, __HIP_MEMORY_SCOPE_AGENT);
}
__device__ __forceinline__ void st_agent_u64(u16* p, u64 v){
  __hip_atomic_store(reinterpret_cast<u64*>(p), v,
                     __ATOMIC_RELAXED, __HIP_MEMORY_SCOPE_AGENT);
}

// ---- per-batch barrier: release fetch_add orders prior sc1 stores; no fences ----
__device__ __forceinline__ void grid_bar(int* bar, int target){
  __syncthreads();
  if (threadIdx.x == 0){
    __hip_atomic_fetch_add(bar, 1, __ATOMIC_RELEASE, __HIP_MEMORY_SCOPE_AGENT);
    unsigned long long t0 = __builtin_amdgcn_s_memrealtime();
    while (__hip_atomic_load(bar, __ATOMIC_RELAXED, __HIP_MEMORY_SCOPE_AGENT) < target){
      __builtin_amdgcn_s_sleep(2);
      if (__builtin_amdgcn_s_memrealtime() - t0 > SPIN_LIMIT) break;
    }
  }
  __syncthreads();
}

// copy a 128x128 fp32 matrix global->LDS, NT threads (GRU + out_kernel path)
template<int NT>
__device__ __forceinline__ void load_W(float* Wl, const float* g, int tid){
  #pragma unroll
  for (int c = 0; c < (HID*HID/4)/NT; ++c){
    int e = (c*NT + tid)*4;
    *reinterpret_cast<float4*>(Wl + e) = *reinterpret_cast<const float4*>(g + e);
  }
}

// split-precision transposed load: W[k][n] fp32 -> WbT[n][k] hi/lo bf16
__device__ __forceinline__ void load_WT_split(u16* WbT, const float* g, int tid){
  #pragma unroll
  for (int c = 0; c < 16; ++c){
    int flat = c*PTHREADS + tid;        // = k*128 + n
    int k = flat >> 7, n = flat & 127;
    float v = g[flat];
    u16 hi = f2bf(v);
    u16 lo = f2bf(v - bf2f(hi));
    WbT[n*WSTRIDE + k]       = hi;
    WbT[WLO + n*WSTRIDE + k] = lo;
  }
}

// one row, 4 cols: o[j] = sum_k yt[rs][k]*Wl[k][fg*4+j]  (fp32, GRU path)
__device__ __forceinline__ void gemm128_1(const float* Wl, const float* yt, int fg, int rs,
                                          float o[4]){
  float a0[4]={0.f,0.f,0.f,0.f};
  #pragma unroll 4
  for (int k=0;k<HID;k+=4){
    float4 ya = *reinterpret_cast<const float4*>(yt + rs*HID + k);
    #pragma unroll
    for (int kk=0;kk<4;++kk){
      const float* wr = Wl + (k+kk)*HID + fg*4;
      float av = (&ya.x)[kk];
      #pragma unroll
      for (int i=0;i<4;++i) a0[i] = fmaf(wr[i], av, a0[i]);
    }
  }
  #pragma unroll
  for (int i=0;i<4;++i) o[i]=a0[i];
}

// two rows (rs, rs+RSTEP), 4 cols — used by out_kernel
template<int RSTEP>
__device__ __forceinline__ void gemm128(const float* Wl, const float* yt, int fg, int rs,
                                        float o0[4], float o1[4]){
  float a0[4]={0.f,0.f,0.f,0.f}, a1[4]={0.f,0.f,0.f,0.f};
  #pragma unroll 4
  for (int k=0;k<HID;k+=4){
    float4 ya = *reinterpret_cast<const float4*>(yt + rs*HID + k);
    float4 yb = *reinterpret_cast<const float4*>(yt + (rs+RSTEP)*HID + k);
    #pragma unroll
    for (int kk=0;kk<4;++kk){
      const float* wr = Wl + (k+kk)*HID + fg*4;
      float av = (&ya.x)[kk];
      float bv = (&yb.x)[kk];
      #pragma unroll
      for (int i=0;i<4;++i){
        float w = wr[i];
        a0[i] = fmaf(w, av, a0[i]);
        a1[i] = fmaf(w, bv, a1[i]);
      }
    }
  }
  #pragma unroll
  for (int i=0;i<4;++i){ o0[i]=a0[i]; o1[i]=a1[i]; }
}

// pack 8 fp32 -> 8 bf16 into yt_bf[rA][off8..off8+7]
__device__ __forceinline__ void pack_y(u16* yt_bf, int rA, int off8, const float y[8]){
  uint4 w;
  w.x = (u32)f2bf(y[0]) | ((u32)f2bf(y[1])<<16);
  w.y = (u32)f2bf(y[2]) | ((u32)f2bf(y[3])<<16);
  w.z = (u32)f2bf(y[4]) | ((u32)f2bf(y[5])<<16);
  w.w = (u32)f2bf(y[6]) | ((u32)f2bf(y[7])<<16);
  *reinterpret_cast<uint4*>(yt_bf + rA*WSTRIDE + off8) = w;
}

// MFMA h-stage: yt_bf holds y (bf16); WbT holds w_gat^T hi/lo.
// Computes h = y @ W (fp32 acc, W exact via hi+lo), writes h bf16 back into
// yt_bf, then wire-stores packed u64 + er epilogue. Caller synced before.
__device__ __forceinline__ void h_stage(u16* yt_bf, const u16* WbT,
    int mt, int nt, int quad, int lc,
    int fg, int rs, int rowF, bool actF,
    u16* __restrict__ h_wr, float* er_l, const float ar4[4])
{
  f32x4 c = {0.f, 0.f, 0.f, 0.f};
  const u16* arow = yt_bf + (mt*16 + lc)*WSTRIDE;
  const u16* brow = WbT  + (nt*16 + lc)*WSTRIDE;
  #pragma unroll
  for (int k0 = 0; k0 < 4; ++k0){
    const int off = k0*32 + quad*8;
    bf16x8 a  = *reinterpret_cast<const bf16x8*>(arow + off);
    bf16x8 bh = *reinterpret_cast<const bf16x8*>(brow + off);
    bf16x8 bl = *reinterpret_cast<const bf16x8*>(brow + WLO + off);
    c = __builtin_amdgcn_mfma_f32_16x16x32_bf16(a, bh, c, 0, 0, 0);
    c = __builtin_amdgcn_mfma_f32_16x16x32_bf16(a, bl, c, 0, 0, 0);
  }
  __syncthreads();              // all A-reads of yt_bf complete
  {
    const int col = nt*16 + lc;
    #pragma unroll
    for (int r = 0; r < 4; ++r)
      yt_bf[(mt*16 + quad*4 + r)*WSTRIDE + col] = f2bf(c[r]);
  }
  __syncthreads();              // h bf16 visible block-wide
  const u64 pk = *reinterpret_cast<const u64*>(yt_bf + rs*WSTRIDE + fg*4);
  if (actF) st_agent_u64(h_wr + (size_t)rowF*HID + fg*4, pk);
  float er = 0.f;
  er = fmaf(bf2f((u16)pk),       ar4[0], er);
  er = fmaf(bf2f((u16)(pk>>16)), ar4[1], er);
  er = fmaf(bf2f((u16)(pk>>32)), ar4[2], er);
  er = fmaf(bf2f((u16)(pk>>48)), ar4[3], er);
  er += __shfl_xor(er,1); er += __shfl_xor(er,2);
  if ((fg & 3) == 0 && actF) er_l[rs*NHEAD + (fg>>2)] = er;
}

// Build CSR (edges sorted by dst); zero the 8 per-batch barrier counters.
__global__ void csr_kernel(const int* __restrict__ src, const int* __restrict__ dst,
                           int* __restrict__ row_start, int* __restrict__ edge_src,
                           int* __restrict__ bar){
  __shared__ int cnt[1024];
  __shared__ int scanb[1024];
  __shared__ int cur[1024];
  int tid = threadIdx.x;
  if (tid < NBATCH*BARSTRIDE) bar[tid] = 0;
  cnt[tid] = 0;
  __syncthreads();
  for (int e = tid; e < NEDGE; e += 1024) atomicAdd(&cnt[dst[e]], 1);
  __syncthreads();
  int v = cnt[tid];
  scanb[tid] = v;
  __syncthreads();
  for (int off=1; off<1024; off<<=1){
    int t = (tid >= off) ? scanb[tid-off] : 0;
    __syncthreads();
    scanb[tid] += t;
    __syncthreads();
  }
  int incl = scanb[tid];
  if (tid < NNODE){ cur[tid] = incl - v; row_start[tid+1] = incl; }
  if (tid == 0) row_start[0] = 0;
  __syncthreads();
  for (int e = tid; e < NEDGE; e += 1024){
    int d = dst[e];
    int pos = atomicAdd(&cur[d], 1);
    edge_src[pos] = src[e];
  }
}

struct PArgs {
  u16* hb0; u16* hb1; float* y_out;
  const int* row_start; const int* edge_src;
  const float* w_gat; const float* a_l; const float* a_r;
  const float* inputs; const float* w_in; const float* b_in;
  const float* w_W; const float* b_W; const float* w_U; const float* b_U;
  int* bar;
};

__global__ void __launch_bounds__(PTHREADS, 4) persist(PArgs p)
{
  __shared__ __align__(16) u16 WbT[2*128*WSTRIDE];  // 68 KB: w_gat^T hi/lo (bf16)
  __shared__ __align__(16) u16 yt_bf[RPB*WSTRIDE];  // 8.5 KB: y then h (bf16)
  __shared__ float zt[RPB*HID];                     // 16 KB: fp32 GRU/LN staging
  __shared__ int   esrc_l[ECAP];
  __shared__ int   eoff[RPB+1];
  __shared__ int   degs_s[RPB];
  __shared__ float er_l[RPB*NHEAD];                 // total ~98 KB -> 1 block/CU
  float* const Wlf = reinterpret_cast<float*>(WbT); // 64 KB fp32 overlay (GRU)

  const int tid  = threadIdx.x;
  const int bat   = blockIdx.x & 7;            // batch index (XCD heuristic)
  const int slot  = blockIdx.x >> 3;           // 0..31
  const int row0  = bat * NNODE + slot * RPB;
  const int nrows = (slot == 31) ? (NNODE - 31*RPB) : RPB;   // 8 or 32
  int* const bar_b = p.bar + bat * BARSTRIDE;
  // layout A (gather): 16 threads x 2 edge-segments per row, 32 rows
  const int tA = tid & 15, seg = (tid >> 4) & 1, rA = tid >> 5;
  const bool actA = rA < nrows;
  const int nA     = slot*RPB + rA;
  const int nAs    = actA ? nA : 0;
  const int sbase  = bat * NNODE;
  const int hd   = tA >> 1;
  const int off8 = tA * 8;
  // layout F (epilogue/LN): 32 col-groups (4 cols) x 32 rows
  const int fg = tid & 31, rs = tid >> 5;
  const bool actF = rs < nrows;
  const int rowF = row0 + rs;
  const int hd2 = fg >> 2, db = (fg & 3) * 4;
  // MFMA ids: 16 waves = 2 M-tiles x 8 N-tiles
  const int wv = tid >> 6, lane = tid & 63, quad = lane >> 4, lc = lane & 15;
  const int mt = wv & 1, nt = wv >> 1;

  // ---- one-time: per-block edge cache ----
  int s0r = 0, degr = 0;
  if (actA){ s0r = p.row_start[nA]; degr = p.row_start[nA+1] - s0r; }
  if ((tid & 31) == 0) degs_s[rA] = degr;
  __syncthreads();
  if (tid == 0){
    int o = 0;
    #pragma unroll
    for (int r = 0; r < RPB; ++r){ eoff[r] = o; o += degs_s[r]; }
    eoff[RPB] = o;
  }
  __syncthreads();
  const int* eptr;
  if (eoff[RPB] <= ECAP){
    const int eb = eoff[rA];
    for (int e = tA + 16*seg; e < degr; e += 32) esrc_l[eb + e] = p.edge_src[s0r + e];
    eptr = esrc_l + eb;
  } else {
    eptr = p.edge_src + s0r;   // statistically never; correctness fallback
  }

  // ---- one-time: per-thread constants ----
  float alA[8];
  #pragma unroll
  for (int i=0;i<8;++i) alA[i] = p.a_l[hd*DHEAD + (tA&1)*8 + i];
  float ar4[4];
  #pragma unroll
  for (int i=0;i<4;++i) ar4[i] = p.a_r[hd2*DHEAD + db + i];

  load_WT_split(WbT, p.w_gat, tid);

  // ---- init: y0 = inputs[:,0]@w_in + b_in ----
  float yb8[8], ya8[8];
  {
    const float x0 = p.inputs[((bat*SEQL + 0)*NNODE + nAs)*2 + 0];
    const float x1 = p.inputs[((bat*SEQL + 0)*NNODE + nAs)*2 + 1];
    #pragma unroll
    for (int i=0;i<8;++i){
      int f = off8 + i;
      yb8[i] = x0*p.w_in[f] + x1*p.w_in[HID+f] + p.b_in[f];
    }
    if (seg == 0) pack_y(yt_bf, rA, off8, yb8);
  }
  __syncthreads();     // yt_bf, WbT, esrc_l staged
  h_stage(yt_bf, WbT, mt, nt, quad, lc, fg, rs, rowF, actF, p.hb0, er_l, ar4);

  int step = 1;
  grid_bar(bar_b, NBLK_B * step); ++step;

  // per-segment edge range (contiguous halves)
  const int half0 = (degr + 1) >> 1;
  const int e_lo = seg ? half0 : 0;
  const int e_hi = seg ? degr  : half0;

  int rd = 0;
  for (int idx = 0; idx < SEQL; ++idx){
    for (int st = 0; st < 4; ++st){
      for (int j = 1; j <= 4; ++j){
        const u16* __restrict__ h_rd = rd ? p.hb1 : p.hb0;
        u16* __restrict__ h_wr       = rd ? p.hb0 : p.hb1;

        // ---- gather: softmax aggregation; el recomputed from bf16 h ----
        float acc[8] = {0.f,0.f,0.f,0.f,0.f,0.f,0.f,0.f};
        float sum = 0.f;
        {
          const float erh = er_l[rA*NHEAD + hd];
          int e = e_lo;
          for (; e + 4 <= e_hi; e += 4){
            u64 L[4], H[4];
            #pragma unroll
            for (int q=0;q<4;++q){
              const int s = sbase + eptr[e+q];
              const u16* hp = h_rd + (size_t)s*HID + off8;
              L[q] = ld_agent_u64(hp);
              H[q] = ld_agent_u64(hp + 4);
            }
            #pragma unroll
            for (int q=0;q<4;++q){
              float hv[8];
              hv[0]=bf2f((u16)L[q]);       hv[1]=bf2f((u16)(L[q]>>16));
              hv[2]=bf2f((u16)(L[q]>>32)); hv[3]=bf2f((u16)(L[q]>>48));
              hv[4]=bf2f((u16)H[q]);       hv[5]=bf2f((u16)(H[q]>>16));
              hv[6]=bf2f((u16)(H[q]>>32)); hv[7]=bf2f((u16)(H[q]>>48));
              float ep = 0.f;
              #pragma unroll
              for (int i=0;i<8;++i) ep = fmaf(alA[i], hv[i], ep);
              ep += __shfl_xor(ep, 1);
              const float x = ep + erh;
              const float w = __expf(fminf(fmaxf(x, 0.2f*x), 30.f));
              sum += w;
              #pragma unroll
              for (int i=0;i<8;++i) acc[i] = fmaf(w, hv[i], acc[i]);
            }
          }
          for (; e < e_hi; ++e){
            const int s = sbase + eptr[e];
            const u16* hp = h_rd + (size_t)s*HID + off8;
            const u64 L = ld_agent_u64(hp);
            const u64 H = ld_agent_u64(hp + 4);
            float hv[8];
            hv[0]=bf2f((u16)L);       hv[1]=bf2f((u16)(L>>16));
            hv[2]=bf2f((u16)(L>>32)); hv[3]=bf2f((u16)(L>>48));
            hv[4]=bf2f((u16)H);       hv[5]=bf2f((u16)(H>>16));
            hv[6]=bf2f((u16)(H>>32)); hv[7]=bf2f((u16)(H>>48));
            float ep = 0.f;
            #pragma unroll
            for (int i=0;i<8;++i) ep = fmaf(alA[i], hv[i], ep);
            ep += __shfl_xor(ep, 1);
            const float x = ep + erh;
            const float w = __expf(fminf(fmaxf(x, 0.2f*x), 30.f));
            sum += w;
            #pragma unroll
            for (int i=0;i<8;++i) acc[i] = fmaf(w, hv[i], acc[i]);
          }
        }
        sum += __shfl_xor(sum, 16);
        #pragma unroll
        for (int i=0;i<8;++i) acc[i] += __shfl_xor(acc[i], 16);
        const float inv = 1.f / (sum + 1e-16f);
        #pragma unroll
        for (int i=0;i<8;++i) acc[i] *= inv;

        // ---- RK4 register update ----
        const bool is5 = (st == 3) && (j == 4);
        float nxt[8];
        if (j == 1){
          #pragma unroll
          for (int i=0;i<8;++i){ ya8[i] = fmaf(DT/6.f, acc[i], yb8[i]);
                                 nxt[i] = fmaf(0.5f*DT, acc[i], yb8[i]); }
        } else if (j == 2){
          #pragma unroll
          for (int i=0;i<8;++i){ ya8[i] = fmaf(DT/3.f, acc[i], ya8[i]);
                                 nxt[i] = fmaf(0.5f*DT, acc[i], yb8[i]); }
        } else if (j == 3){
          #pragma unroll
          for (int i=0;i<8;++i){ ya8[i] = fmaf(DT/3.f, acc[i], ya8[i]);
                                 nxt[i] = fmaf(DT, acc[i], yb8[i]); }
        } else {
          #pragma unroll
          for (int i=0;i<8;++i) nxt[i] = fmaf(DT/6.f, acc[i], ya8[i]);
          if (!is5){
            #pragma unroll
            for (int i=0;i<8;++i) yb8[i] = nxt[i];
          }
        }

        if (!is5){
          if (seg == 0) pack_y(yt_bf, rA, off8, nxt);
          __syncthreads();
          h_stage(yt_bf, WbT, mt, nt, quad, lc, fg, rs, rowF, actF, h_wr, er_l, ar4);
          grid_bar(bar_b, NBLK_B * step); ++step;
          rd ^= 1;
          continue;
        }

        // ---- end of interval: GRU (fp32 vector) / LN / state handoff ----
        const bool last = (idx == SEQL-1);
        if (seg == 0){
          *reinterpret_cast<float4*>(zt + rA*HID + off8)     = make_float4(nxt[0],nxt[1],nxt[2],nxt[3]);
          *reinterpret_cast<float4*>(zt + rA*HID + off8 + 4) = make_float4(nxt[4],nxt[5],nxt[6],nxt[7]);
        }
        float z4[4];
        if (idx > 0){
          load_W<PTHREADS>(Wlf, p.w_W, tid);     // overlays WbT (restored below)
          __syncthreads();                       // zt(y_new) + w_W ready
          gemm128_1(Wlf, zt, fg, rs, z4);        // z = y_new @ w_W
          __syncthreads();                       // gemm reads done
          {
            const float x0 = p.inputs[((bat*SEQL + idx)*NNODE + nAs)*2 + 0];
            const float x1 = p.inputs[((bat*SEQL + idx)*NNODE + nAs)*2 + 1];
            if (seg == 0){
              float hv[8];
              #pragma unroll
              for (int i=0;i<8;++i){
                int f = off8 + i;
                hv[i] = x0*p.w_in[f] + x1*p.w_in[HID+f] + p.b_in[f];
              }
              *reinterpret_cast<float4*>(zt + rA*HID + off8)     = make_float4(hv[0],hv[1],hv[2],hv[3]);
              *reinterpret_cast<float4*>(zt + rA*HID + off8 + 4) = make_float4(hv[4],hv[5],hv[6],hv[7]);
            }
          }
          load_W<PTHREADS>(Wlf, p.w_U, tid);
          __syncthreads();
          float u4[4];
          gemm128_1(Wlf, zt, fg, rs, u4);        // u = h_in @ w_U
          #pragma unroll
          for (int i=0;i<4;++i)
            z4[i] = tanhf(z4[i] + u4[i] + p.b_W[fg*4+i] + p.b_U[fg*4+i]);
        } else {
          __syncthreads();                       // zt(y_new) visible in F layout
          #pragma unroll
          for (int i=0;i<4;++i) z4[i] = zt[rs*HID + fg*4 + i];
        }
        // LayerNorm over 128 features (32 fg lanes)
        {
          float sv=0.f, qv=0.f;
          #pragma unroll
          for (int i=0;i<4;++i){ sv+=z4[i]; qv+=z4[i]*z4[i]; }
          #pragma unroll
          for (int off=1; off<32; off<<=1){
            sv += __shfl_xor(sv, off); qv += __shfl_xor(qv, off);
          }
          float mu = sv*(1.f/HID);
          float r  = rsqrtf(qv*(1.f/HID) - mu*mu + 1e-5f);
          #pragma unroll
          for (int i=0;i<4;++i) z4[i] = (z4[i]-mu)*r;
        }
        __syncthreads();                         // all zt readers done
        *reinterpret_cast<float4*>(zt + rs*HID + fg*4) = make_float4(z4[0],z4[1],z4[2],z4[3]);
        if (last){
          if (actF)
            *reinterpret_cast<float4*>(p.y_out + (size_t)rowF*HID + fg*4) =
                make_float4(z4[0],z4[1],z4[2],z4[3]);
          // final stage: no more barriers; blocks exit uniformly
        } else {
          __syncthreads();                       // zt(z) visible
          if (idx > 0) load_WT_split(WbT, p.w_gat, tid);  // restore w_gat^T hi/lo
          #pragma unroll
          for (int i=0;i<8;++i) yb8[i] = zt[rA*HID + off8 + i];  // new y state (fp32)
          if (seg == 0) pack_y(yt_bf, rA, off8, yb8);
          __syncthreads();
          h_stage(yt_bf, WbT, mt, nt, quad, lc, fg, rs, rowF, actF, h_wr, er_l, ar4);
          grid_bar(bar_b, NBLK_B * step); ++step;
          rd ^= 1;
        }
      }
    }
  }
}

// out = tanh(ret @ w_o1 + b_o1) @ w_o2 + b_o2, fp32 output
__global__ void __launch_bounds__(256, 2) out_kernel(
    const float* __restrict__ y_base,
    const float* __restrict__ w_o1, const float* __restrict__ b_o1,
    const float* __restrict__ w_o2, const float* __restrict__ b_o2,
    float* __restrict__ out)
{
  __shared__ float Wl[HID*HID];
  __shared__ float yt[ORPB*HID];
  const int tid = threadIdx.x;
  const int row0 = blockIdx.x * ORPB;
  const int rA = tid >> 4, tA = tid & 15;
  const int rowA = row0 + rA;
  {
    float4 v0 = *reinterpret_cast<const float4*>(y_base + rowA*HID + tA*8);
    float4 v1 = *reinterpret_cast<const float4*>(y_base + rowA*HID + tA*8 + 4);
    *reinterpret_cast<float4*>(yt + rA*HID + tA*8)     = v0;
    *reinterpret_cast<float4*>(yt + rA*HID + tA*8 + 4) = v1;
  }
  load_W<256>(Wl, w_o1, tid);
  __syncthreads();
  const int fg = tid & 31, rs = tid >> 5;
  float t0[4], t1[4];
  gemm128<8>(Wl, yt, fg, rs, t0, t1);
  #pragma unroll
  for (int i=0;i<4;++i){
    float bb = b_o1[fg*4+i];
    t0[i] = tanhf(t0[i] + bb);
    t1[i] = tanhf(t1[i] + bb);
  }
  __syncthreads();
  *reinterpret_cast<float4*>(yt + rs*HID + fg*4)     = make_float4(t0[0],t0[1],t0[2],t0[3]);
  *reinterpret_cast<float4*>(yt + (rs+8)*HID + fg*4) = make_float4(t1[0],t1[1],t1[2],t1[3]);
  load_W<256>(Wl, w_o2, tid);
  __syncthreads();
  float o0[4], o1[4];
  gemm128<8>(Wl, yt, fg, rs, o0, o1);
  const int rowF0 = row0 + rs, rowF1 = row0 + rs + 8;
  *reinterpret_cast<float4*>(out + rowF0*HID + fg*4) =
      make_float4(o0[0]+b_o2[fg*4+0], o0[1]+b_o2[fg*4+1], o0[2]+b_o2[fg*4+2], o0[3]+b_o2[fg*4+3]);
  *reinterpret_cast<float4*>(out + rowF1*HID + fg*4) =
      make_float4(o1[0]+b_o2[fg*4+0], o1[1]+b_o2[fg*4+1], o1[2]+b_o2[fg*4+2], o1[3]+b_o2[fg*4+3]);
}

extern "C" void kernel_launch(void* const* d_in, const int* in_sizes, int n_in,
                              void* d_out, int out_size, void* d_ws, size_t ws_size,
                              hipStream_t stream)
{
  const float* inputs = (const float*)d_in[0];
  const int* src      = (const int*)d_in[1];
  const int* dst      = (const int*)d_in[2];
  const float* w_in   = (const float*)d_in[3];
  const float* b_in   = (const float*)d_in[4];
  const float* w_gat  = (const float*)d_in[5];
  const float* a_l    = (const float*)d_in[6];
  const float* a_r    = (const float*)d_in[7];
  const float* w_W    = (const float*)d_in[8];
  const float* b_W    = (const float*)d_in[9];
  const float* w_U    = (const float*)d_in[10];
  const float* b_U    = (const float*)d_in[11];
  const float* w_o1   = (const float*)d_in[12];
  const float* b_o1   = (const float*)d_in[13];
  const float* w_o2   = (const float*)d_in[14];
  const float* b_o2   = (const float*)d_in[15];

  const size_t RH = (size_t)NROWS * HID;    // 1,024,000
  float* y_out = reinterpret_cast<float*>(d_ws);            // RH floats
  u16*   hbuf  = reinterpret_cast<u16*>(y_out + RH);        // 2*RH bf16
  u16*   hb0   = hbuf;
  u16*   hb1   = hbuf + RH;
  int*   I     = reinterpret_cast<int*>(hbuf + 2*RH);
  int* row_start = I;
  int* edge_src  = I + 1024;
  int* bar       = I + 1024 + NEDGE;

  size_t need = RH*sizeof(float) + 2*RH*sizeof(u16)
              + (size_t)(1024 + NEDGE + NBATCH*BARSTRIDE)*sizeof(int);
  if (ws_size < need) return;

  csr_kernel<<<1, 1024, 0, stream>>>(src, dst, row_start, edge_src, bar);

  PArgs pa;
  pa.hb0 = hb0; pa.hb1 = hb1; pa.y_out = y_out;
  pa.row_start = row_start; pa.edge_src = edge_src;
  pa.w_gat = w_gat; pa.a_l = a_l; pa.a_r = a_r;
  pa.inputs = inputs; pa.w_in = w_in; pa.b_in = b_in;
  pa.w_W = w_W; pa.b_W = b_W; pa.w_U = w_U; pa.b_U = b_U;
  pa.bar = bar;

  persist<<<NBLK_P, PTHREADS, 0, stream>>>(pa);

  out_kernel<<<NBLK_O, 256, 0, stream>>>(y_out, w_o1, b_o1, w_o2, b_o2, (float*)d_out);
}